// Round 1
// 1539.164 us; speedup vs baseline: 2.4748x; 2.4748x over previous
//
#include <hip/hip_runtime.h>

#define THREADS 256
#define TOK 16
#define XS 260    // fp32 x row stride (256 + 4 pad) for exact recompute
#define ALD 264   // bf16 A row stride (256 + 8 pad) -> conflict-free ds_read_b128
#define DELTA 8e-3f   // argmax candidate window; bf16-split sim err max ~7e-4 << DELTA/2

// Output section bases (element offsets into flat d_out), reference return order:
// quantized (8,4096,1024) | indices (8,4096,4) | quant (8,4096,4,256) |
// avg_code_probs (8,4096,1024) | x (8,4096,1024)
#define OFF_IDX 33554432ull
#define OFF_Q2  33685504ull
#define OFF_AVG 67239936ull
#define OFF_X   100794368ull

typedef short short8v __attribute__((ext_vector_type(8)));
typedef float f32x4  __attribute__((ext_vector_type(4)));

// ---- bf16 round-to-nearest-even split helpers ----
__device__ __forceinline__ unsigned short f2bf(float f) {
  unsigned int u = __float_as_uint(f);
  unsigned int r = (u + 0x7fffu + ((u >> 16) & 1u)) >> 16;
  return (unsigned short)r;
}
__device__ __forceinline__ float bf2f(unsigned short h) {
  return __uint_as_float(((unsigned int)h) << 16);
}

// Exact replica of the reference's fp32 accumulation order (single forward FMA
// chain over d ascending) — used only for the rare multi-candidate argmax.
__device__ __forceinline__ float ref_dot256(const float* __restrict__ xr,
                                            const float* __restrict__ cr) {
  float acc = 0.f;
#pragma unroll
  for (int d = 0; d < 256; ++d)
    acc = __fmaf_rn(xr[d], cr[d], acc);
  return acc;
}

// ---- prep: codebooks fp32 [4][1024][256] -> bf16 hi/lo planes in workspace ----
// ws layout: hi = ws[0 .. 2^20), lo = ws[2^20 .. 2^21)  (ushort units; 4 MiB total)
__global__ __launch_bounds__(256)
void cb_prep(const float* __restrict__ cb, unsigned short* __restrict__ ws) {
  int i = blockIdx.x * 256 + threadIdx.x;          // 262144 threads x float4
  float4 v = ((const float4*)cb)[i];
  ushort4 h, lo;
  h.x = f2bf(v.x); lo.x = f2bf(v.x - bf2f(h.x));
  h.y = f2bf(v.y); lo.y = f2bf(v.y - bf2f(h.y));
  h.z = f2bf(v.z); lo.z = f2bf(v.z - bf2f(h.z));
  h.w = f2bf(v.w); lo.w = f2bf(v.w - bf2f(h.w));
  ((ushort4*)ws)[i] = h;
  ((ushort4*)(ws + (1u << 20)))[i] = lo;
}

// ---- main fused kernel: 16 tokens/block, 4 waves, wave w owns codes [256w,256w+256) ----
// MFMA 16x16x32 bf16, 3-term split (xh*ch + xl*ch + xh*cl) -> fp32-grade sims.
// C/D mapping (measured): col = lane&15 (code), row = (lane>>4)*4 + reg (token).
// A frag: row = lane&15 (token), k = (lane>>4)*8 + b.  B frag: col = lane&15 (code),
// k = (lane>>4)*8 + b  -> 16B contiguous loads from [code][d] row-major bf16 planes.
__global__ __launch_bounds__(THREADS, 2)
void ahq_mfma(const float* __restrict__ x,
              const float* __restrict__ cb,
              const unsigned short* __restrict__ cbh,
              const float* __restrict__ temp,
              float* __restrict__ out) {
  __shared__ float xs[TOK * XS];
  __shared__ unsigned short Ah[TOK * ALD];
  __shared__ unsigned short Al[TOK * ALD];
  __shared__ float red_m[4][TOK];
  __shared__ float red_s[4][TOK];
  __shared__ int   clist[TOK][16];
  __shared__ int   ccnt[TOK];
  __shared__ int   idx_all[TOK][4];

  const int t    = threadIdx.x;
  const int wave = t >> 6;
  const int lane = t & 63;
  const int cl   = lane & 15;       // code-in-tile / A row
  const int g    = lane >> 4;       // k-group; owns tokens 4g..4g+3 in C/D
  const int dl   = g * 8;           // k offset within a 32-wide k-step
  const int bs0  = blockIdx.x * TOK;

  const float tau = fmaxf(temp[0], 0.04f);
  const float invtau = 1.0f / tau;

  float* out_q   = out;
  float* out_idx = out + OFF_IDX;
  float* out_q2  = out + OFF_Q2;
  float* out_avg = out + OFF_AVG;
  float* out_x   = out + OFF_X;

  f32x4 avg[16];
#pragma unroll
  for (int j = 0; j < 16; ++j) avg[j] = (f32x4)(0.f);

  for (int l = 0; l < 4; ++l) {
    if (t < TOK) ccnt[t] = 0;

    // ---- stage x slab: fp32 to xs (exact path) + bf16 hi/lo to Ah/Al + passthrough ----
    {
      const float4* xg = (const float4*)x;
      float4* xo = (float4*)out_x;
#pragma unroll
      for (int it = 0; it < 4; ++it) {
        int f = t + THREADS * it;            // 0..1023 float4s of [16][64]
        int row = f >> 6, col4 = f & 63;
        size_t gi = (size_t)(bs0 + row) * 256 + (size_t)l * 64 + col4;
        float4 v = xg[gi];
        xo[gi] = v;                          // x passthrough, coalesced
        float* dst = &xs[row * XS + col4 * 4];
        dst[0] = v.x; dst[1] = v.y; dst[2] = v.z; dst[3] = v.w;
        ushort4 h, lo;
        h.x = f2bf(v.x); lo.x = f2bf(v.x - bf2f(h.x));
        h.y = f2bf(v.y); lo.y = f2bf(v.y - bf2f(h.y));
        h.z = f2bf(v.z); lo.z = f2bf(v.z - bf2f(h.z));
        h.w = f2bf(v.w); lo.w = f2bf(v.w - bf2f(h.w));
        *(ushort4*)&Ah[row * ALD + col4 * 4] = h;
        *(ushort4*)&Al[row * ALD + col4 * 4] = lo;
      }
    }
    __syncthreads();   // S1

    // ---- MFMA GEMM: wave computes sim[16 tok][256 codes] as 16 tiles of 16x16 ----
    f32x4 acc[16];
#pragma unroll
    for (int j = 0; j < 16; ++j) acc[j] = (f32x4)(0.f);

    const unsigned short* pbh = cbh + ((size_t)l << 18)
                                    + (size_t)(wave * 256 + cl) * 256 + dl;
    const unsigned short* pbl = pbh + (1u << 20);       // lo plane
    const unsigned short* pah = &Ah[cl * ALD + dl];
    const unsigned short* pal = &Al[cl * ALD + dl];

#pragma unroll 1
    for (int ks = 0; ks < 8; ++ks) {
      short8v ah = *(const short8v*)(pah + ks * 32);
      short8v al = *(const short8v*)(pal + ks * 32);
#pragma unroll
      for (int j = 0; j < 16; ++j) {
        short8v bh = *(const short8v*)(pbh + j * 4096 + ks * 32);
        short8v bl = *(const short8v*)(pbl + j * 4096 + ks * 32);
        acc[j] = __builtin_amdgcn_mfma_f32_16x16x32_bf16(ah, bh, acc[j], 0, 0, 0);
        acc[j] = __builtin_amdgcn_mfma_f32_16x16x32_bf16(al, bh, acc[j], 0, 0, 0);
        acc[j] = __builtin_amdgcn_mfma_f32_16x16x32_bf16(ah, bl, acc[j], 0, 0, 0);
      }
    }

    // ---- per-token max: in-lane over 16 tiles, then xor-reduce over code lanes ----
    float M4[4];
#pragma unroll
    for (int r = 0; r < 4; ++r) {
      float m = acc[0][r];
#pragma unroll
      for (int j = 1; j < 16; ++j) m = fmaxf(m, acc[j][r]);
      M4[r] = m;
    }
#pragma unroll
    for (int off = 1; off <= 8; off <<= 1)
#pragma unroll
      for (int r = 0; r < 4; ++r) M4[r] = fmaxf(M4[r], __shfl_xor(M4[r], off, 64));
    if (cl == 0)
#pragma unroll
      for (int r = 0; r < 4; ++r) red_m[wave][g * 4 + r] = M4[r];
    __syncthreads();   // S2
#pragma unroll
    for (int r = 0; r < 4; ++r) {
      int tok = g * 4 + r;
      M4[r] = fmaxf(fmaxf(red_m[0][tok], red_m[1][tok]),
                    fmaxf(red_m[2][tok], red_m[3][tok]));
    }

    // ---- push delta-window candidates (raw sims, before exp overwrite) ----
#pragma unroll
    for (int r = 0; r < 4; ++r) {
      int tok = g * 4 + r;
      float thr = M4[r] - DELTA;
#pragma unroll
      for (int j = 0; j < 16; ++j) {
        if (acc[j][r] >= thr) {
          int pos = atomicAdd(&ccnt[tok], 1);
          if (pos < 16) clist[tok][pos] = wave * 256 + j * 16 + cl;
        }
      }
    }

    // ---- exp + row sum ----
    float S4[4];
#pragma unroll
    for (int r = 0; r < 4; ++r) {
      float s = 0.f;
#pragma unroll
      for (int j = 0; j < 16; ++j) {
        float e = __expf((acc[j][r] - M4[r]) * invtau);
        acc[j][r] = e; s += e;
      }
      S4[r] = s;
    }
#pragma unroll
    for (int off = 1; off <= 8; off <<= 1)
#pragma unroll
      for (int r = 0; r < 4; ++r) S4[r] += __shfl_xor(S4[r], off, 64);
    if (cl == 0)
#pragma unroll
      for (int r = 0; r < 4; ++r) red_s[wave][g * 4 + r] = S4[r];
    __syncthreads();   // S3

    // ---- avg_code_probs accumulation ----
#pragma unroll
    for (int r = 0; r < 4; ++r) {
      int tok = g * 4 + r;
      float Z = red_s[0][tok] + red_s[1][tok] + red_s[2][tok] + red_s[3][tok];
      float invZ = 1.0f / Z;
#pragma unroll
      for (int j = 0; j < 16; ++j) avg[j][r] += acc[j][r] * invZ;
    }

    // ---- argmax: sole candidate, or ref-order fp32 recompute (exact indices) ----
    if ((t & 15) == 0) {
      int m = t >> 4;
      int cnt = ccnt[m]; if (cnt > 16) cnt = 16;
      int fin;
      if (cnt == 1) {
        fin = clist[m][0];
      } else {
        float best = -3.4e38f; int bi = 0x7fffffff;
        for (int q = 0; q < cnt; ++q) {
          int ci = clist[m][q];
          float s = ref_dot256(&xs[m * XS], cb + ((size_t)l << 18) + (size_t)ci * 256);
          if (s > best || (s == best && ci < bi)) { best = s; bi = ci; }
        }
        fin = bi;
      }
      out_idx[(size_t)(bs0 + m) * 4 + l] = (float)fin;
      idx_all[m][l] = fin;
    }
    __syncthreads();   // S4: protect restage + red_*/ccnt reuse + idx_all
  }

  // ---- avg_code_probs stores: 16-lane code runs -> 64B coalesced segments ----
#pragma unroll
  for (int r = 0; r < 4; ++r) {
    size_t rb = (size_t)(bs0 + g * 4 + r) * 1024 + (size_t)(wave * 256 + cl);
#pragma unroll
    for (int j = 0; j < 16; ++j)
      out_avg[rb + j * 16] = avg[j][r] * 0.25f;
  }

  // ---- hard_q gather -> quantized AND quant (identical flat content) ----
  {
    const float4* cb4 = (const float4*)cb;
    float4* o0 = (float4*)out_q;
    float4* o2 = (float4*)out_q2;
#pragma unroll
    for (int it = 0; it < 16; ++it) {
      int f = t + THREADS * it;            // 0..4095 float4s of [16][256]
      int row = f >> 8, col4 = f & 255;
      int ll = col4 >> 6, d4 = col4 & 63;
      int idx = idx_all[row][ll];
      float4 v = cb4[(((size_t)ll * 1024 + idx) << 6) + d4];
      size_t o = (size_t)(bs0 + row) * 256 + col4;
      o0[o] = v;
      o2[o] = v;
    }
  }
}

extern "C" void kernel_launch(void* const* d_in, const int* in_sizes, int n_in,
                              void* d_out, int out_size, void* d_ws, size_t ws_size,
                              hipStream_t stream) {
  const float* x    = (const float*)d_in[0];
  const float* cb   = (const float*)d_in[1];
  const float* temp = (const float*)d_in[2];
  unsigned short* ws = (unsigned short*)d_ws;   // needs 4 MiB for bf16 hi/lo planes
  hipLaunchKernelGGL(cb_prep, dim3(1024), dim3(256), 0, stream, cb, ws);
  hipLaunchKernelGGL(ahq_mfma, dim3(32768 / TOK), dim3(THREADS), 0, stream,
                     x, cb, ws, temp, (float*)d_out);
}

// Round 2
// 1166.420 us; speedup vs baseline: 3.2657x; 1.3196x over previous
//
#include <hip/hip_runtime.h>

#define THREADS 256
#define TOK 16
#define XS 260    // fp32 x row stride (256 + 4 pad) for exact recompute
#define ALD 264   // bf16 A row stride (256 + 8 pad)
#define DELTA 8e-3f   // argmax candidate window; bf16-split sim err max ~7e-4 << DELTA/2

// Output section bases (element offsets into flat d_out), reference return order:
// quantized (8,4096,1024) | indices (8,4096,4) | quant (8,4096,4,256) |
// avg_code_probs (8,4096,1024) | x (8,4096,1024)
#define OFF_IDX 33554432ull
#define OFF_Q2  33685504ull
#define OFF_AVG 67239936ull
#define OFF_X   100794368ull

typedef short short8v __attribute__((ext_vector_type(8)));
typedef float f32x4  __attribute__((ext_vector_type(4)));

// ---- bf16 round-to-nearest-even split helpers ----
__device__ __forceinline__ unsigned short f2bf(float f) {
  unsigned int u = __float_as_uint(f);
  unsigned int r = (u + 0x7fffu + ((u >> 16) & 1u)) >> 16;
  return (unsigned short)r;
}
__device__ __forceinline__ float bf2f(unsigned short h) {
  return __uint_as_float(((unsigned int)h) << 16);
}

// Exact replica of the reference's fp32 accumulation order (single forward FMA
// chain over d ascending) — used only for the rare multi-candidate argmax.
__device__ __forceinline__ float ref_dot256(const float* __restrict__ xr,
                                            const float* __restrict__ cr) {
  float acc = 0.f;
#pragma unroll
  for (int d = 0; d < 256; ++d)
    acc = __fmaf_rn(xr[d], cr[d], acc);
  return acc;
}

// ---- prep: codebooks fp32 [4][1024][256] -> SWIZZLED bf16 hi/lo planes ----
// Cell layout: cell = ((l*8 + ks)*64 + (wave*16 + j))*64 + lane, each cell =
// 8 bf16 = 16 B. Cell content: cb[l][wave*256 + j*16 + (lane&15)]
//                                [ks*32 + (lane>>4)*8 .. +8)
// => every wave-level B-fragment load in the main kernel is one fully
// contiguous, 16B/lane, 1 KiB transaction.
// hi plane at ws[0 .. 2^20), lo plane at ws[2^20 .. 2^21) (ushort units, 4 MiB).
__global__ __launch_bounds__(256)
void cb_prep(const float* __restrict__ cb, unsigned short* __restrict__ ws) {
  int tid = blockIdx.x * 256 + threadIdx.x;      // 131072 cells
  int lane = tid & 63;
  int wj   = (tid >> 6) & 63;
  int ks   = (tid >> 12) & 7;
  int l    = tid >> 15;
  int code = ((wj >> 4) << 8) + ((wj & 15) << 4) + (lane & 15);
  int k0   = (ks << 5) + ((lane >> 4) << 3);
  const float* s = cb + ((((size_t)l << 10) + code) << 8) + k0;
  float4 a = *(const float4*)(s);
  float4 b = *(const float4*)(s + 4);
  float v[8] = {a.x, a.y, a.z, a.w, b.x, b.y, b.z, b.w};
  unsigned short h[8], lo[8];
#pragma unroll
  for (int e = 0; e < 8; ++e) {
    h[e]  = f2bf(v[e]);
    lo[e] = f2bf(v[e] - bf2f(h[e]));
  }
  ushort4* dh = (ushort4*)(ws + (size_t)tid * 8);
  ushort4* dl = (ushort4*)(ws + (1u << 20) + (size_t)tid * 8);
  dh[0] = make_ushort4(h[0], h[1], h[2], h[3]);
  dh[1] = make_ushort4(h[4], h[5], h[6], h[7]);
  dl[0] = make_ushort4(lo[0], lo[1], lo[2], lo[3]);
  dl[1] = make_ushort4(lo[4], lo[5], lo[6], lo[7]);
}

// B-fragment load: quarter-stage = 4 code-tiles x 2 planes = 8 coalesced 1KiB loads
#define LDB(ks_, q_, H, L) { \
  const unsigned short* _p = pbh + (ks_) * 32768 + (q_) * 2048; \
  const unsigned short* _q = pbl + (ks_) * 32768 + (q_) * 2048; \
  _Pragma("unroll") for (int _j = 0; _j < 4; ++_j) { \
    H[_j] = *(const short8v*)(_p + _j * 512); \
    L[_j] = *(const short8v*)(_q + _j * 512); } }

// 3-term MFMA for a quarter-stage (code tiles q*4 .. q*4+3)
#define COMPQ(q_, H, L) { \
  _Pragma("unroll") for (int _j = 0; _j < 4; ++_j) { \
    int _t = (q_) * 4 + _j; \
    acc[_t] = __builtin_amdgcn_mfma_f32_16x16x32_bf16(ah_c, H[_j], acc[_t], 0, 0, 0); \
    acc[_t] = __builtin_amdgcn_mfma_f32_16x16x32_bf16(al_c, H[_j], acc[_t], 0, 0, 0); \
    acc[_t] = __builtin_amdgcn_mfma_f32_16x16x32_bf16(ah_c, L[_j], acc[_t], 0, 0, 0); } }

// ---- main fused kernel: 16 tokens/block, 4 waves, wave w owns codes [256w,256w+256) ----
// MFMA 16x16x32 bf16, 3-term split (xh*ch + xl*ch + xh*cl) -> fp32-grade sims.
// C/D mapping (measured): col = lane&15 (code), row = (lane>>4)*4 + reg (token).
__global__ __launch_bounds__(THREADS, 2)
void ahq_mfma(const float* __restrict__ x,
              const float* __restrict__ cb,
              const unsigned short* __restrict__ cbh,
              const float* __restrict__ temp,
              float* __restrict__ out) {
  __shared__ float xs[TOK * XS];
  __shared__ unsigned short Ah[TOK * ALD];
  __shared__ unsigned short Al[TOK * ALD];
  __shared__ float red_m[4][TOK];
  __shared__ float red_s[4][TOK];
  __shared__ int   clist[TOK][16];
  __shared__ int   ccnt[TOK];
  __shared__ int   idx_all[TOK][4];

  const int t    = threadIdx.x;
  const int wave = t >> 6;
  const int lane = t & 63;
  const int cl   = lane & 15;       // code-in-tile
  const int g    = lane >> 4;       // k-group; owns tokens 4g..4g+3 in C/D
  const int dl   = g * 8;           // k offset within a 32-wide k-step
  const int bs0  = blockIdx.x * TOK;

  const float tau = fmaxf(temp[0], 0.04f);
  const float invtau = 1.0f / tau;

  float* out_q   = out;
  float* out_idx = out + OFF_IDX;
  float* out_q2  = out + OFF_Q2;
  float* out_avg = out + OFF_AVG;
  float* out_x   = out + OFF_X;

  f32x4 avg[16];
#pragma unroll
  for (int j = 0; j < 16; ++j) avg[j] = (f32x4)(0.f);

  for (int l = 0; l < 4; ++l) {
    // ---- B prologue: issue layer's first quarter-stage before staging ----
    const unsigned short* pbh = cbh + ((size_t)l << 18) + (wave << 13) + (lane << 3);
    const unsigned short* pbl = pbh + (1u << 20);
    short8v h0[4], l0[4], h1[4], l1[4];
    LDB(0, 0, h0, l0);

    if (t < TOK) ccnt[t] = 0;

    // ---- stage x slab: fp32 to xs (exact path) + bf16 hi/lo to Ah/Al + passthrough ----
    {
      const float4* xg = (const float4*)x;
      float4* xo = (float4*)out_x;
#pragma unroll
      for (int it = 0; it < 4; ++it) {
        int f = t + THREADS * it;            // 0..1023 float4s of [16][64]
        int row = f >> 6, col4 = f & 63;
        size_t gi = (size_t)(bs0 + row) * 256 + (size_t)l * 64 + col4;
        float4 v = xg[gi];
        xo[gi] = v;                          // x passthrough, coalesced
        float* dst = &xs[row * XS + col4 * 4];
        dst[0] = v.x; dst[1] = v.y; dst[2] = v.z; dst[3] = v.w;
        ushort4 h, lo;
        h.x = f2bf(v.x); lo.x = f2bf(v.x - bf2f(h.x));
        h.y = f2bf(v.y); lo.y = f2bf(v.y - bf2f(h.y));
        h.z = f2bf(v.z); lo.z = f2bf(v.z - bf2f(h.z));
        h.w = f2bf(v.w); lo.w = f2bf(v.w - bf2f(h.w));
        *(ushort4*)&Ah[row * ALD + col4 * 4] = h;
        *(ushort4*)&Al[row * ALD + col4 * 4] = lo;
      }
    }
    __syncthreads();   // S1

    // ---- MFMA GEMM: software-pipelined quarter-stages (4 j-tiles each) ----
    f32x4 acc[16];
#pragma unroll
    for (int j = 0; j < 16; ++j) acc[j] = (f32x4)(0.f);

    const unsigned short* pah = &Ah[cl * ALD + dl];
    const unsigned short* pal = &Al[cl * ALD + dl];
    short8v ah_c = *(const short8v*)pah;
    short8v al_c = *(const short8v*)pal;

#pragma unroll
    for (int ks = 0; ks < 8; ++ks) {
      LDB(ks, 1, h1, l1);
      COMPQ(0, h0, l0);
      LDB(ks, 2, h0, l0);
      COMPQ(1, h1, l1);
      LDB(ks, 3, h1, l1);
      COMPQ(2, h0, l0);
      short8v ah_n = ah_c, al_n = al_c;
      if (ks < 7) {
        LDB(ks + 1, 0, h0, l0);
        ah_n = *(const short8v*)(pah + (ks + 1) * 32);
        al_n = *(const short8v*)(pal + (ks + 1) * 32);
      }
      COMPQ(3, h1, l1);
      ah_c = ah_n; al_c = al_n;
    }

    // ---- per-token max: in-lane over 16 tiles, then xor-reduce over code lanes ----
    float M4[4];
#pragma unroll
    for (int r = 0; r < 4; ++r) {
      float m = acc[0][r];
#pragma unroll
      for (int j = 1; j < 16; ++j) m = fmaxf(m, acc[j][r]);
      M4[r] = m;
    }
#pragma unroll
    for (int off = 1; off <= 8; off <<= 1)
#pragma unroll
      for (int r = 0; r < 4; ++r) M4[r] = fmaxf(M4[r], __shfl_xor(M4[r], off, 64));
    if (cl == 0)
#pragma unroll
      for (int r = 0; r < 4; ++r) red_m[wave][g * 4 + r] = M4[r];
    __syncthreads();   // S2
#pragma unroll
    for (int r = 0; r < 4; ++r) {
      int tok = g * 4 + r;
      M4[r] = fmaxf(fmaxf(red_m[0][tok], red_m[1][tok]),
                    fmaxf(red_m[2][tok], red_m[3][tok]));
    }

    // ---- push delta-window candidates (raw sims, before exp overwrite) ----
#pragma unroll
    for (int r = 0; r < 4; ++r) {
      int tok = g * 4 + r;
      float thr = M4[r] - DELTA;
#pragma unroll
      for (int j = 0; j < 16; ++j) {
        if (acc[j][r] >= thr) {
          int pos = atomicAdd(&ccnt[tok], 1);
          if (pos < 16) clist[tok][pos] = wave * 256 + j * 16 + cl;
        }
      }
    }

    // ---- exp + row sum ----
    float S4[4];
#pragma unroll
    for (int r = 0; r < 4; ++r) {
      float s = 0.f;
#pragma unroll
      for (int j = 0; j < 16; ++j) {
        float e = __expf((acc[j][r] - M4[r]) * invtau);
        acc[j][r] = e; s += e;
      }
      S4[r] = s;
    }
#pragma unroll
    for (int off = 1; off <= 8; off <<= 1)
#pragma unroll
      for (int r = 0; r < 4; ++r) S4[r] += __shfl_xor(S4[r], off, 64);
    if (cl == 0)
#pragma unroll
      for (int r = 0; r < 4; ++r) red_s[wave][g * 4 + r] = S4[r];
    __syncthreads();   // S3

    // ---- avg_code_probs accumulation ----
#pragma unroll
    for (int r = 0; r < 4; ++r) {
      int tok = g * 4 + r;
      float Z = red_s[0][tok] + red_s[1][tok] + red_s[2][tok] + red_s[3][tok];
      float invZ = 1.0f / Z;
#pragma unroll
      for (int j = 0; j < 16; ++j) avg[j][r] += acc[j][r] * invZ;
    }

    // ---- argmax: sole candidate, or ref-order fp32 recompute (exact indices) ----
    if ((t & 15) == 0) {
      int m = t >> 4;
      int cnt = ccnt[m]; if (cnt > 16) cnt = 16;
      int fin;
      if (cnt == 1) {
        fin = clist[m][0];
      } else {
        float best = -3.4e38f; int bi = 0x7fffffff;
        for (int q = 0; q < cnt; ++q) {
          int ci = clist[m][q];
          float s = ref_dot256(&xs[m * XS], cb + ((size_t)l << 18) + (size_t)ci * 256);
          if (s > best || (s == best && ci < bi)) { best = s; bi = ci; }
        }
        fin = bi;
      }
      out_idx[(size_t)(bs0 + m) * 4 + l] = (float)fin;
      idx_all[m][l] = fin;
    }
    __syncthreads();   // S4: protect restage + red_*/ccnt reuse + idx_all
  }

  // ---- avg_code_probs stores: 16-lane code runs -> 64B coalesced segments ----
#pragma unroll
  for (int r = 0; r < 4; ++r) {
    size_t rb = (size_t)(bs0 + g * 4 + r) * 1024 + (size_t)(wave * 256 + cl);
#pragma unroll
    for (int j = 0; j < 16; ++j)
      out_avg[rb + j * 16] = avg[j][r] * 0.25f;
  }

  // ---- hard_q gather -> quantized AND quant (identical flat content) ----
  {
    const float4* cb4 = (const float4*)cb;
    float4* o0 = (float4*)out_q;
    float4* o2 = (float4*)out_q2;
#pragma unroll
    for (int it = 0; it < 16; ++it) {
      int f = t + THREADS * it;            // 0..4095 float4s of [16][256]
      int row = f >> 8, col4 = f & 255;
      int ll = col4 >> 6, d4 = col4 & 63;
      int idx = idx_all[row][ll];
      float4 v = cb4[(((size_t)ll * 1024 + idx) << 6) + d4];
      size_t o = (size_t)(bs0 + row) * 256 + col4;
      o0[o] = v;
      o2[o] = v;
    }
  }
}

extern "C" void kernel_launch(void* const* d_in, const int* in_sizes, int n_in,
                              void* d_out, int out_size, void* d_ws, size_t ws_size,
                              hipStream_t stream) {
  const float* x    = (const float*)d_in[0];
  const float* cb   = (const float*)d_in[1];
  const float* temp = (const float*)d_in[2];
  unsigned short* ws = (unsigned short*)d_ws;   // needs 4 MiB for bf16 hi/lo planes
  hipLaunchKernelGGL(cb_prep, dim3(512), dim3(256), 0, stream, cb, ws);
  hipLaunchKernelGGL(ahq_mfma, dim3(32768 / TOK), dim3(THREADS), 0, stream,
                     x, cb, ws, temp, (float*)d_out);
}